// Round 6
// baseline (705.035 us; speedup 1.0000x reference)
//
#include <hip/hip_runtime.h>

// RecurrentModel: 2-layer GRU stack. Persistent-weight team design.
// 32 teams x 8 blocks. Team = (batch-group of 128) x (time-chunk of 16).
// Block j of a team owns hidden cols [32j,32j+32) of BOTH layers; its weight
// row-slices live in LDS for the whole kernel. Per step, teams exchange
// h-state slices via d_ws buffers + per-team atomic flags (sc1/RELAXED-AGENT).
// R1: per-team flag padding (512B), relaxed spin, s_sleep(2).
// R2: fence-free rendezvous — sc1 per-access coherent exchange, no wbl2/inv.
// R3: SINGLE rendezvous per step (flag1 redundant; h1 drain hides under L0).
// R4: wave-per-m16 decomposition (no duplicated A-frag loads), TBS 32->16.
// R5: XCD-local sc0 asm path — FAILED correctness; fully reverted.
// R6: MALL-transaction diet, memory model unchanged (verified sc1 builtins):
//     (a) fragment-major hx layout [w][kc][1KB]: A-frag refresh loads are
//         64-lane contiguous 512B per instruction (fully-used 128B reqs);
//     (b) K-permutation p=2*l15+cg inside each 32-col block: producer's two
//         cg values land in adjacent bytes -> one packed 4B store per row
//         (was 2x2B scattered). Same perm applied to whh0/wih1/whh1 LDS
//         staging (content permuted, addresses unchanged) and h_init gather.
//     ~10x fewer MALL reqs/step at identical protocol & arithmetic.
#define T_    256
#define B_    256
#define IN_   64
#define HID_  512
#define LS_   256
#define G3_   768
#define TBS_  16     // timesteps per team
#define MBT_  128    // batch rows per team
#define WP_   264    // LDS weight row pitch in shorts (528B: 16B-aligned, 2-way-bank free)
#define FSTRIDE_ 128 // ints per team flag region (512 B)

typedef short bf16x8v __attribute__((ext_vector_type(8)));
typedef float f32x4  __attribute__((ext_vector_type(4)));
typedef unsigned long long u64;

#define MFMA_B16(A, B, C) __builtin_amdgcn_mfma_f32_16x16x32_bf16(A, B, C, 0, 0, 0)

__device__ __forceinline__ unsigned short f2bf(float f) {
  union { float f; unsigned u; } v; v.f = f;
  unsigned r = v.u + 0x7fffu + ((v.u >> 16) & 1u);   // RNE
  return (unsigned short)(r >> 16);
}
__device__ __forceinline__ float sigm(float x) { return 1.0f / (1.0f + __expf(-x)); }
__device__ __forceinline__ float tanh_f(float x) {
  x = fminf(fmaxf(x, -15.0f), 15.0f);
  float e = __expf(-2.0f * x);
  return (1.0f - e) / (1.0f + e);
}

// ---- device-coherent (sc1) primitives, verified R2-R4 ----
// consumer: one A-fragment (16B logical) = two contiguous-lane 8B halves.
// layout block (w,kc) is 1KB; lane (l15,quad) lo-half at (quad*16+l15)*8,
// hi-half at +512. A wave's 8B instruction covers 512B contiguous.
__device__ __forceinline__ bf16x8v ld_frag_coh(const char* tb, int w8kc, int l15, int quad) {
  const char* p = tb + ((size_t)w8kc << 10) + (size_t)((((quad << 4) + l15)) << 3);
  union { u64 q[2]; bf16x8v v; } u;
  u.q[0] = __hip_atomic_load((const u64*)p,         __ATOMIC_RELAXED, __HIP_MEMORY_SCOPE_AGENT);
  u.q[1] = __hip_atomic_load((const u64*)(p + 512), __ATOMIC_RELAXED, __HIP_MEMORY_SCOPE_AGENT);
  return u.v;
}
// producer: packed 4B store of (cg0,cg1) at physical cols p0=2*l15, p0+1.
// byte off within block: ((p>>3)*16 + (m&15))*8 + (p&4)*128 + (p&3)*2
__device__ __forceinline__ void st_pair_coh(char* tb, int m, int j, int l15, unsigned pack) {
  const int p0 = l15 << 1;
  char* p = tb + ((size_t)((((m >> 4) << 3) + j)) << 10)
               + (size_t)(((((p0 >> 3) << 4) + (m & 15)) << 3) + ((p0 & 4) << 7) + ((p0 & 3) << 1));
  __hip_atomic_store((unsigned*)p, pack, __ATOMIC_RELAXED, __HIP_MEMORY_SCOPE_AGENT);
}

// ---------------- merged prep: weight conv + reset sniff + flags + W_c ------
__global__ void prep_all(const float* __restrict__ whh0, const float* __restrict__ wih1,
                         const float* __restrict__ whh1, const unsigned char* __restrict__ rst,
                         const float* __restrict__ W_lin, const float* __restrict__ b_lin,
                         const float* __restrict__ w_ih0, const float* __restrict__ b_ih0,
                         unsigned short* __restrict__ dst, unsigned short* __restrict__ wc,
                         float* __restrict__ bc, int* __restrict__ flagp,
                         int* __restrict__ flags) {
  const int bx = blockIdx.x;
  const int tid = threadIdx.x;
  if (bx < 1152) {
    // bf16 conversion of [whh0 | wih1 | whh1]
    const int idx = bx * 512 + tid;
    const int N1 = G3_ * LS_;
    if (idx < 3 * N1) {
      float v;
      if (idx < N1)            v = whh0[idx];
      else if (idx < 2 * N1)   v = wih1[idx - N1];
      else                     v = whh1[idx - 2 * N1];
      dst[idx] = f2bf(v);
    }
    if (bx == 1 && tid < 32) flags[tid * FSTRIDE_] = 0;  // per-team padded f0
    if (bx == 0) {
      __shared__ int f;
      if (tid == 0) f = 0;
      __syncthreads();
      int any = 0;
      for (int i = 0; i < 8; ++i) {
        int off = tid * 8 + i;
        if ((off & 3) && rst[off]) any = 1;
      }
      if (any) atomicOr(&f, 1);
      __syncthreads();
      if (tid == 0) *flagp = f;   // 1 => byte-packed reset
    }
  } else {
    // fused embed W_c = w_ih0 @ W_lin, b_c; one wave per output row n
    const int n = (bx - 1152) * 8 + (tid >> 6);
    const int i = tid & 63;
    const float* wrow = w_ih0 + (size_t)n * HID_;
    float acc = 0.f;
    for (int h = 0; h < HID_; ++h) acc += wrow[h] * W_lin[h * IN_ + i];
    wc[n * IN_ + i] = f2bf(acc);
    float pb = 0.f;
    for (int h = i; h < HID_; h += 64) pb += wrow[h] * b_lin[h];
#pragma unroll
    for (int off = 32; off > 0; off >>= 1) pb += __shfl_down(pb, off);
    if (i == 0) bc[n] = pb + b_ih0[n];
  }
}

// ---------------- main: persistent-weight recurrent kernel ------------------
__global__ __launch_bounds__(512, 2) void gru_main(
    const float* __restrict__ obs, const unsigned char* __restrict__ rst,
    const float* __restrict__ h_init,
    const unsigned short* __restrict__ wc,     // [768][64] bf16 (global, L2-hot)
    const unsigned short* __restrict__ whh0g,  // [768][256] bf16
    const unsigned short* __restrict__ wih1g, const unsigned short* __restrict__ whh1g,
    const float* __restrict__ bcp, const float* __restrict__ bhh0,
    const float* __restrict__ bih1, const float* __restrict__ bhh1,
    const int* __restrict__ flagp, int* __restrict__ flag0,
    unsigned short* __restrict__ hx0, unsigned short* __restrict__ hx1,
    float* __restrict__ out) {

  // Weight slices, persistent all-kernel: [whh0 | wih1 | whh1], 96 rows x 264 pitch
  __shared__ __align__(16) unsigned short wlds[3 * 96 * WP_];   // 152064 B
  __shared__ int s_sm[128];
  __shared__ int s_start_sh;

  const int tid  = threadIdx.x;
  const int lane = tid & 63;
  const int w    = tid >> 6;            // wave = m16 row-tile 0..7 (128 rows)
  const int l15  = lane & 15;
  const int quad = lane >> 4;

  // block -> (team, slice j); bx&7 ~ XCD heuristic (correctness-independent)
  const int x  = blockIdx.x;
  const int cx = x & 7, m8 = x >> 3;
  const int j  = m8 & 7;                // col-slice 0..7
  const int team = cx * 4 + (m8 >> 3);  // 0..31 (4 teams per XCD)
  const int bg = team & 1, tc = team >> 1;
  const int b0 = bg * MBT_, t0 = tc * TBS_;

  // per-team private flag word (512-B stride kills cross-team line contention)
  int* f0 = flag0 + team * FSTRIDE_;

  const int flag = *flagp;
#define RVAL(i) (rst[flag ? (i) : ((i) << 2)] != 0)

  // ---- stage weight slices into LDS (once), applying the K-permutation:
  // LDS K-position kc*32+p holds source hidden kc*32 + (p&1)*16 + (p>>1).
  // (content permuted; addresses/banking unchanged)
#pragma unroll
  for (int q = 0; q < 3; ++q) {
    const unsigned short* src = (q == 0) ? whh0g : (q == 1) ? wih1g : whh1g;
    for (int cid = tid; cid < 96 * 32; cid += 512) {      // 16B chunks
      int lr = cid >> 5, ch = cid & 31;                   // row, chunk
      int g = lr >> 5, cc = lr & 31;
      int grow = (g << 8) + (j << 5) + cc;                // g*256 + j*32 + cc
      int kc = ch >> 2, q4 = (ch & 3) << 2;               // K-32 block, p-quad base
      const unsigned short* s = &src[(size_t)grow * 256 + (kc << 5) + q4];
      u64 A = *(const u64*)s;          // hidden q4..q4+3     (cg=0 side)
      u64 B = *(const u64*)(s + 16);   // hidden 16+q4..+3    (cg=1 side)
      u64 o0 = (A & 0xffffull) | ((B & 0xffffull) << 16) |
               (((A >> 16) & 0xffffull) << 32) | (((B >> 16) & 0xffffull) << 48);
      u64 o1 = ((A >> 32) & 0xffffull) | (((B >> 32) & 0xffffull) << 16) |
               (((A >> 48) & 0xffffull) << 32) | (((B >> 48) & 0xffffull) << 48);
      unsigned short* d = &wlds[(q * 96 + lr) * WP_ + (ch << 3)];
      *(u64*)d = o0; *((u64*)(d + 4)) = o1;
    }
  }

  // ---- per-lane biases, both col-16 groups of the 32-col slice ----
  float b0r[2], b0z[2], b0i[2], b0h[2], b1r[2], b1z[2], b1i[2], b1h[2];
#pragma unroll
  for (int cg = 0; cg < 2; ++cg) {
    const int c = j * 32 + cg * 16 + l15;
    b0r[cg] = bcp[c] + bhh0[c];
    b0z[cg] = bcp[256 + c] + bhh0[256 + c];
    b0i[cg] = bcp[512 + c];
    b0h[cg] = bhh0[512 + c];
    b1r[cg] = bih1[c] + bhh1[c];
    b1z[cg] = bih1[256 + c] + bhh1[256 + c];
    b1i[cg] = bih1[512 + c];
    b1h[cg] = bhh1[512 + c];
  }

  // ---- team-uniform safe start (last reset <= t0 across the 128 batch rows) ----
  if (tid < 128) {
    int s = 0;
    for (int tt = t0; tt >= 1; --tt) {
      if (RVAL(tt * B_ + b0 + tid)) { s = tt; break; }
    }
    s_sm[tid] = s;
  }
  __syncthreads();
  if (tid == 0) {
    int s = s_sm[0];
    for (int k = 1; k < 128; ++k) s = s < s_sm[k] ? s : s_sm[k];
    s_start_sh = s;
  }
  __syncthreads();
  const int s_start = s_start_sh;   // identical across the 8 sibling blocks

  // ---- init A-fragments (rows w*16+l15, K-permuted gather) and fp32 carries ----
  bf16x8v h0A[8], h1A[8];
  const bf16x8v z8 = {0, 0, 0, 0, 0, 0, 0, 0};
#pragma unroll
  for (int kc = 0; kc < 8; ++kc) { h0A[kc] = z8; h1A[kc] = z8; }
  float h0v[2][4], h1v[2][4];
#pragma unroll
  for (int cg = 0; cg < 2; ++cg)
#pragma unroll
    for (int r = 0; r < 4; ++r) { h0v[cg][r] = 0.f; h1v[cg][r] = 0.f; }
  if (s_start == 0) {
    const float* hrow = h_init + (size_t)(b0 + w * 16 + l15) * HID_;
#pragma unroll
    for (int kc = 0; kc < 8; ++kc) {
      bf16x8v a, b;
#pragma unroll
      for (int e = 0; e < 8; ++e) {
        const int p  = (quad << 3) + e;
        const int lk = ((p & 1) << 4) + (p >> 1);   // logical hidden within 32
        a[e] = (short)f2bf(hrow[(kc << 5) + lk]);
        b[e] = (short)f2bf(hrow[256 + (kc << 5) + lk]);
      }
      h0A[kc] = a; h1A[kc] = b;
    }
#pragma unroll
    for (int cg = 0; cg < 2; ++cg)
#pragma unroll
      for (int r = 0; r < 4; ++r) {
        const int m = w * 16 + quad * 4 + r;
        const int c = j * 32 + cg * 16 + l15;
        h0v[cg][r] = h_init[(size_t)(b0 + m) * HID_ + c];
        h1v[cg][r] = h_init[(size_t)(b0 + m) * HID_ + 256 + c];
      }
  }

  // weight row pointers at cg=0 (cg=1 = +16*WP_ shorts, folded into offset)
  const unsigned short* wR0 = &wlds[(0 * 96 + 0 * 32 + l15) * WP_];
  const unsigned short* wZ0 = &wlds[(0 * 96 + 1 * 32 + l15) * WP_];
  const unsigned short* wN0 = &wlds[(0 * 96 + 2 * 32 + l15) * WP_];
  const unsigned short* iR1 = &wlds[(1 * 96 + 0 * 32 + l15) * WP_];
  const unsigned short* iZ1 = &wlds[(1 * 96 + 1 * 32 + l15) * WP_];
  const unsigned short* iN1 = &wlds[(1 * 96 + 2 * 32 + l15) * WP_];
  const unsigned short* hR1 = &wlds[(2 * 96 + 0 * 32 + l15) * WP_];
  const unsigned short* hZ1 = &wlds[(2 * 96 + 1 * 32 + l15) * WP_];
  const unsigned short* hN1 = &wlds[(2 * 96 + 2 * 32 + l15) * WP_];
#define CGO_ (16 * WP_)

  // obs software pipeline: raw f32x4 regs for the CURRENT step, prefetched
  f32x4 ou0a, ou0b, ou1a, ou1b;
  {
    const float* po = obs + ((size_t)s_start * B_ + b0 + w * 16 + l15) * IN_;
    ou0a = __builtin_nontemporal_load((const f32x4*)(po + quad * 8));
    ou0b = __builtin_nontemporal_load((const f32x4*)(po + quad * 8 + 4));
    ou1a = __builtin_nontemporal_load((const f32x4*)(po + 32 + quad * 8));
    ou1b = __builtin_nontemporal_load((const f32x4*)(po + 32 + quad * 8 + 4));
  }

  for (int t = s_start; t < t0 + TBS_; ++t) {
    const int  kk = t - s_start + 1;          // 1-based team step counter
    const bool wr = (t >= t0);
    const bool rs0 = RVAL(t * B_ + b0 + w * 16 + l15);   // A-row mask
    bool rse[4];
#pragma unroll
    for (int r = 0; r < 4; ++r) rse[r] = RVAL(t * B_ + b0 + w * 16 + quad * 4 + r);

    // ============ layer 0 ============
    f32x4 ar[2], az[2], ani[2], anh[2];
#pragma unroll
    for (int cg = 0; cg < 2; ++cg) {
      ar[cg] = (f32x4){0.f, 0.f, 0.f, 0.f};
      az[cg] = ar[cg]; ani[cg] = ar[cg]; anh[cg] = ar[cg];
    }
    // input side: obs @ W_c^T (K=64, unpermuted obs K-space)
#pragma unroll
    for (int kc = 0; kc < 2; ++kc) {
      f32x4 u0 = kc ? ou1a : ou0a;
      f32x4 u1 = kc ? ou1b : ou0b;
      bf16x8v oA;
#pragma unroll
      for (int e = 0; e < 4; ++e) { oA[e] = (short)f2bf(u0[e]); oA[4 + e] = (short)f2bf(u1[e]); }
#pragma unroll
      for (int cg = 0; cg < 2; ++cg) {
        const size_t wo = (size_t)(j * 32 + cg * 16 + l15) * 64 + kc * 32 + quad * 8;
        bf16x8v br = *(const bf16x8v*)&wc[wo];
        bf16x8v bz = *(const bf16x8v*)&wc[wo + (size_t)256 * 64];
        bf16x8v bn = *(const bf16x8v*)&wc[wo + (size_t)512 * 64];
        ar[cg]  = MFMA_B16(oA, br, ar[cg]);
        az[cg]  = MFMA_B16(oA, bz, az[cg]);
        ani[cg] = MFMA_B16(oA, bn, ani[cg]);
      }
    }
    // h side: (mask*h0[t-1]) @ whh0^T (K=256, LDS weights, K-permuted both sides)
#pragma unroll
    for (int kc = 0; kc < 8; ++kc) {
      bf16x8v am = rs0 ? z8 : h0A[kc];
      const int o = kc * 32 + quad * 8;
#pragma unroll
      for (int cg = 0; cg < 2; ++cg) {
        ar[cg]  = MFMA_B16(am, *(const bf16x8v*)&wR0[o + cg * CGO_], ar[cg]);
        az[cg]  = MFMA_B16(am, *(const bf16x8v*)&wZ0[o + cg * CGO_], az[cg]);
        anh[cg] = MFMA_B16(am, *(const bf16x8v*)&wN0[o + cg * CGO_], anh[cg]);
      }
    }
    // epilogue 0: fp32 carry, publish slice (one packed 4B sc1 store per row)
    {
      char* tbw = (char*)(hx0 + (size_t)(team * 2 + (kk & 1)) * (MBT_ * 256));
#pragma unroll
      for (int r = 0; r < 4; ++r) {
        const int m = w * 16 + quad * 4 + r;
        float hvv[2];
#pragma unroll
        for (int cg = 0; cg < 2; ++cg) {
          float rr = sigm(ar[cg][r] + b0r[cg]);
          float zz = sigm(az[cg][r] + b0z[cg]);
          float nn = tanh_f(ani[cg][r] + b0i[cg] + rr * (anh[cg][r] + b0h[cg]));
          float hp = rse[r] ? 0.f : h0v[cg][r];
          hvv[cg] = (1.f - zz) * nn + zz * hp;
          h0v[cg][r] = hvv[cg];
        }
        st_pair_coh(tbw, m, j, l15,
                    (unsigned)f2bf(hvv[0]) | ((unsigned)f2bf(hvv[1]) << 16));
      }
    }
    // ---- SINGLE rendezvous: the barrier's vmcnt(0) drain covers h0[kk]
    // stores AND last iter's h1[kk-1] stores (hidden under L0 compute).
    // f0>=8kk therefore implies: all siblings published h0[kk] and h1[kk-1].
    __syncthreads();
    if (tid == 0) {
      __hip_atomic_fetch_add(f0, 1, __ATOMIC_RELAXED, __HIP_MEMORY_SCOPE_AGENT);
      int cap = 0;
      while (__hip_atomic_load(f0, __ATOMIC_RELAXED, __HIP_MEMORY_SCOPE_AGENT)
                 < 8 * kk && cap < (1 << 16)) { __builtin_amdgcn_s_sleep(2); ++cap; }
      // no acquire fence: reader loads below are per-access coherent (sc1)
    }
    __syncthreads();
    // A-frag refresh FIRST (heads the VMEM queue; L1 MFMA waits on these):
    // h0n[t] (fresh) and h1n[t-1] — fragment-major contiguous coherent loads
    {
      const char* tb0 = (const char*)(hx0 + (size_t)(team * 2 + (kk & 1)) * (MBT_ * 256));
#pragma unroll
      for (int kc = 0; kc < 8; ++kc)
        h0A[kc] = ld_frag_coh(tb0, w * 8 + kc, l15, quad);
      if (kk >= 2) {
        const char* tb1 =
            (const char*)(hx1 + (size_t)(team * 2 + ((kk - 1) & 1)) * (MBT_ * 256));
#pragma unroll
        for (int kc = 0; kc < 8; ++kc)
          h1A[kc] = ld_frag_coh(tb1, w * 8 + kc, l15, quad);
      }
    }
    // deferred out stores (off the rendezvous path): L0[t] and L1[t-1]
    if (wr) {
#pragma unroll
      for (int cg = 0; cg < 2; ++cg)
#pragma unroll
        for (int r = 0; r < 4; ++r) {
          const int m = w * 16 + quad * 4 + r;
          __builtin_nontemporal_store(h0v[cg][r],
              &out[((size_t)t * B_ + b0 + m) * HID_ + j * 32 + cg * 16 + l15]);
        }
    }
    if (t - 1 >= t0) {
#pragma unroll
      for (int cg = 0; cg < 2; ++cg)
#pragma unroll
        for (int r = 0; r < 4; ++r) {
          const int m = w * 16 + quad * 4 + r;
          __builtin_nontemporal_store(h1v[cg][r],
              &out[((size_t)(t - 1) * B_ + b0 + m) * HID_ + 256 + j * 32 + cg * 16 + l15]);
        }
    }
    // prefetch obs for step t+1
    {
      const int tn = (t + 1 < t0 + TBS_) ? t + 1 : t;
      const float* po = obs + ((size_t)tn * B_ + b0 + w * 16 + l15) * IN_;
      ou0a = __builtin_nontemporal_load((const f32x4*)(po + quad * 8));
      ou0b = __builtin_nontemporal_load((const f32x4*)(po + quad * 8 + 4));
      ou1a = __builtin_nontemporal_load((const f32x4*)(po + 32 + quad * 8));
      ou1b = __builtin_nontemporal_load((const f32x4*)(po + 32 + quad * 8 + 4));
    }

    // ============ layer 1 ============
#pragma unroll
    for (int cg = 0; cg < 2; ++cg) {
      ar[cg] = (f32x4){0.f, 0.f, 0.f, 0.f};
      az[cg] = ar[cg]; ani[cg] = ar[cg]; anh[cg] = ar[cg];
    }
#pragma unroll
    for (int kc = 0; kc < 8; ++kc) {
      bf16x8v ai_ = h0A[kc];                 // h0n[t], unmasked
      bf16x8v am  = rs0 ? z8 : h1A[kc];      // mask*h1[t-1]
      const int o = kc * 32 + quad * 8;
#pragma unroll
      for (int cg = 0; cg < 2; ++cg) {
        ar[cg]  = MFMA_B16(ai_, *(const bf16x8v*)&iR1[o + cg * CGO_], ar[cg]);
        az[cg]  = MFMA_B16(ai_, *(const bf16x8v*)&iZ1[o + cg * CGO_], az[cg]);
        ani[cg] = MFMA_B16(ai_, *(const bf16x8v*)&iN1[o + cg * CGO_], ani[cg]);
        ar[cg]  = MFMA_B16(am, *(const bf16x8v*)&hR1[o + cg * CGO_], ar[cg]);
        az[cg]  = MFMA_B16(am, *(const bf16x8v*)&hZ1[o + cg * CGO_], az[cg]);
        anh[cg] = MFMA_B16(am, *(const bf16x8v*)&hN1[o + cg * CGO_], anh[cg]);
      }
    }
    // epilogue 1: publish slice; NO barrier/signal here (folded into next
    // step's rendezvous — drain hides under next step's L0 compute)
    {
      char* tbw = (char*)(hx1 + (size_t)(team * 2 + (kk & 1)) * (MBT_ * 256));
#pragma unroll
      for (int r = 0; r < 4; ++r) {
        const int m = w * 16 + quad * 4 + r;
        float hvv[2];
#pragma unroll
        for (int cg = 0; cg < 2; ++cg) {
          float rr = sigm(ar[cg][r] + b1r[cg]);
          float zz = sigm(az[cg][r] + b1z[cg]);
          float nn = tanh_f(ani[cg][r] + b1i[cg] + rr * (anh[cg][r] + b1h[cg]));
          float hp = rse[r] ? 0.f : h1v[cg][r];
          hvv[cg] = (1.f - zz) * nn + zz * hp;
          h1v[cg][r] = hvv[cg];
        }
        st_pair_coh(tbw, m, j, l15,
                    (unsigned)f2bf(hvv[0]) | ((unsigned)f2bf(hvv[1]) << 16));
      }
    }
    // (buffer-overwrite safety: publishes at step kk occur after wait(kk-1)
    //  or wait(kk), which implies all sibling reads of the half being
    //  overwritten are complete — unchanged R3/R4 protocol.)
  }
  // final deferred out store: L1[t0+TBS-1]
  {
    const int tl = t0 + TBS_ - 1;
#pragma unroll
    for (int cg = 0; cg < 2; ++cg)
#pragma unroll
      for (int r = 0; r < 4; ++r) {
        const int m = w * 16 + quad * 4 + r;
        __builtin_nontemporal_store(h1v[cg][r],
            &out[((size_t)tl * B_ + b0 + m) * HID_ + 256 + j * 32 + cg * 16 + l15]);
      }
  }
#undef RVAL
#undef CGO_
}

extern "C" void kernel_launch(void* const* d_in, const int* in_sizes, int n_in,
                              void* d_out, int out_size, void* d_ws, size_t ws_size,
                              hipStream_t stream) {
  const float* obs    = (const float*)d_in[0];
  const unsigned char* rst = (const unsigned char*)d_in[1];
  const float* h_init = (const float*)d_in[2];
  const float* W_lin  = (const float*)d_in[3];
  const float* b_lin  = (const float*)d_in[4];
  const float* w_ih0  = (const float*)d_in[5];
  const float* w_hh0  = (const float*)d_in[6];
  const float* b_ih0  = (const float*)d_in[7];
  const float* b_hh0  = (const float*)d_in[8];
  const float* w_ih1  = (const float*)d_in[9];
  const float* w_hh1  = (const float*)d_in[10];
  const float* b_ih1  = (const float*)d_in[11];
  const float* b_hh1  = (const float*)d_in[12];

  // workspace carve (re-initialized every launch; ws is re-poisoned by harness)
  char* w = (char*)d_ws;
  unsigned short* wcp   = (unsigned short*)(w);              // 98304 B
  unsigned short* whh0b = (unsigned short*)(w + 98304);      // 393216 B
  unsigned short* wih1b = (unsigned short*)(w + 491520);
  unsigned short* whh1b = (unsigned short*)(w + 884736);
  float*          bcp   = (float*)(w + 1277952);             // 3072 B
  int*            flagp = (int*)(w + 1281024);               // 16 B
  int*            flags = (int*)(w + 1281088);               // 32 teams * 512 B padded flags
  unsigned short* hx0   = (unsigned short*)(w + 1310720);    // 32*2*128*256*2 = 4 MiB
  unsigned short* hx1   = (unsigned short*)(w + 1310720 + 4194304);
  // total ws usage: 1310720 + 8 MiB ≈ 9.7 MB

  prep_all<<<1152 + 96, 512, 0, stream>>>(w_hh0, w_ih1, w_hh1, rst,
                                          W_lin, b_lin, w_ih0, b_ih0,
                                          whh0b, wcp, bcp, flagp, flags);
  gru_main<<<256, 512, 0, stream>>>(obs, rst, h_init, wcp, whh0b, wih1b, whh1b,
                                    bcp, b_hh0, b_ih1, b_hh1, flagp,
                                    flags, hx0, hx1, (float*)d_out);
}